// Round 1
// baseline (51771.991 us; speedup 1.0000x reference)
//
#include <hip/hip_runtime.h>

#define LAYERS 6
#define BB 10
#define TT 2048
#define II 128
#define HH 256
#define GPL 32          // blocks per layer
#define DEPTH 8         // h ring-buffer depth (power of 2)
#define NTH 256
#define NCOL 8          // h-columns per block
#define NROW 32         // gate rows per block (4 gates x 8 cols)
#define HCSTR 520       // padded LDS stride for h_cat rows
#define REDSTR 36       // padded stride for reduction scratch

struct Smem {
    union {
        float hc[BB][HCSTR];            // staged [x_t | h_below | h_own] per batch
        float red[NROW * BB][REDSTR];   // partial-sum scratch (aliased, phase-disjoint)
    } u;
    float gates[NROW][BB];
    float cst[NCOL][BB];
    float bias_s[NROW];
};

__device__ __forceinline__ float fsig(float x) { return 1.0f / (1.0f + __expf(-x)); }
__device__ __forceinline__ float ftanh(float x) {
    x = fminf(fmaxf(x, -15.0f), 15.0f);
    float e = __expf(2.0f * x);
    return (e - 1.0f) / (e + 1.0f);
}

// CH4 = float4-chunks per (thread, batch): 4 -> K=512 (layers 1..5), 3 -> K=384 (layer 0)
template <int CH4>
__device__ void run_layer(Smem& sm, int l, int s,
                          const float* __restrict__ x,
                          const float* __restrict__ h0,
                          const float* __restrict__ c0,
                          const float* __restrict__ Wih0,
                          const float* __restrict__ Wih,
                          const float* __restrict__ Whh,
                          const float* __restrict__ bih,
                          const float* __restrict__ bhh,
                          float* __restrict__ out,
                          int* prog, float* hring)
{
    constexpr int K = CH4 * 128;   // 512 or 384
    constexpr int F = K - HH;      // 256 or 128 (input-feature width)
    const int tid = threadIdx.x;
    const int kc  = tid & 31;      // K-split lane (32 chunks)
    const int rg  = tid >> 3 >> 2; // row group 0..7 (tid>>5)

    const float* WihL = (F == II) ? Wih0 : (Wih + (size_t)(l - 1) * 4 * HH * HH);
    const float* WhhL = Whh + (size_t)l * 4 * HH * HH;

    // ---- persistent weight registers: 4 rows x CH4 float4 ----
    float4 wreg[4][CH4];
    const int kcm = kc % CH4;
    #pragma unroll
    for (int ri = 0; ri < 4; ++ri) {
        const int rloc = rg * 4 + ri;                       // 0..31
        const int gr = (rloc >> 3) * HH + s * NCOL + (rloc & 7); // global gate row
        #pragma unroll
        for (int i4 = 0; i4 < CH4; ++i4) {
            int st = i4 + kcm; if (st >= CH4) st -= CH4;    // bank-stagger order
            const int k0 = (kc * CH4 + st) * 4;
            float tmp[4];
            #pragma unroll
            for (int c = 0; c < 4; ++c) {
                const int kk = k0 + c;
                tmp[c] = (kk < F) ? WihL[(size_t)gr * F + kk]
                                  : WhhL[(size_t)gr * HH + (kk - F)];
            }
            wreg[ri][i4] = make_float4(tmp[0], tmp[1], tmp[2], tmp[3]);
        }
    }
    if (tid < NROW) {
        const int gr = (tid >> 3) * HH + s * NCOL + (tid & 7);
        sm.bias_s[tid] = bih[l * 4 * HH + gr] + bhh[l * 4 * HH + gr];
    }
    if (tid < NCOL * BB) {
        const int j = tid & 7, b = tid >> 3;
        sm.cst[j][b] = c0[((size_t)l * BB + b) * HH + s * NCOL + j];
    }
    __syncthreads();

    float* const myring = hring + (size_t)l * DEPTH * BB * HH;

    for (int t = 0; t < TT; ++t) {
        // ---- A: flag waits (3 independent spinners in 3 different waves) ----
        if (tid == 0 && t > 0) {
            const int tgt = GPL * t;            // all own-layer blocks finished t-1
            while (__hip_atomic_load(&prog[l], __ATOMIC_ACQUIRE, __HIP_MEMORY_SCOPE_AGENT) < tgt)
                __builtin_amdgcn_s_sleep(1);
        }
        if (tid == 64 && l > 0) {
            const int tgt = GPL * (t + 1);      // below layer finished t
            while (__hip_atomic_load(&prog[l - 1], __ATOMIC_ACQUIRE, __HIP_MEMORY_SCOPE_AGENT) < tgt)
                __builtin_amdgcn_s_sleep(1);
        }
        if (tid == 128 && l < LAYERS - 1 && t >= DEPTH) {
            const int tgt = GPL * (t - DEPTH + 1);  // back-pressure: consumer done with slot
            while (__hip_atomic_load(&prog[l + 1], __ATOMIC_ACQUIRE, __HIP_MEMORY_SCOPE_AGENT) < tgt)
                __builtin_amdgcn_s_sleep(1);
        }
        __syncthreads();

        // ---- B: stage h_cat = [x_t | h_below , h_own] into LDS ----
        if (F == II) {  // layer 0: x feature block
            for (int q = tid; q < BB * (II / 4); q += NTH) {
                const int b = q >> 5, qq = q & 31;
                *(float4*)&sm.u.hc[b][qq * 4] =
                    *(const float4*)&x[((size_t)b * TT + t) * II + qq * 4];
            }
        } else {
            const float* below = hring + ((size_t)(l - 1) * DEPTH + (t & (DEPTH - 1))) * BB * HH;
            for (int q = tid; q < BB * (HH / 4); q += NTH) {
                const int b = q >> 6, qq = q & 63;
                *(float4*)&sm.u.hc[b][qq * 4] = *(const float4*)&below[b * HH + qq * 4];
            }
        }
        {
            const float* own = (t == 0) ? (h0 + (size_t)l * BB * HH)
                                        : (myring + (size_t)((t - 1) & (DEPTH - 1)) * BB * HH);
            for (int q = tid; q < BB * (HH / 4); q += NTH) {
                const int b = q >> 6, qq = q & 63;
                *(float4*)&sm.u.hc[b][F + qq * 4] = *(const float4*)&own[b * HH + qq * 4];
            }
        }
        __syncthreads();

        // ---- C1: register-blocked partial dots (4 rows x 10 batches, K-chunk of CH4*4) ----
        float acc[4][BB];
        #pragma unroll
        for (int ri = 0; ri < 4; ++ri)
            #pragma unroll
            for (int b = 0; b < BB; ++b) acc[ri][b] = 0.0f;

        #pragma unroll
        for (int i4 = 0; i4 < CH4; ++i4) {
            int st = i4 + kcm; if (st >= CH4) st -= CH4;
            const int col = (kc * CH4 + st) * 4;
            #pragma unroll
            for (int b = 0; b < BB; ++b) {
                const float4 h4 = *(const float4*)&sm.u.hc[b][col];
                #pragma unroll
                for (int ri = 0; ri < 4; ++ri) {
                    acc[ri][b] = fmaf(wreg[ri][i4].x, h4.x, acc[ri][b]);
                    acc[ri][b] = fmaf(wreg[ri][i4].y, h4.y, acc[ri][b]);
                    acc[ri][b] = fmaf(wreg[ri][i4].z, h4.z, acc[ri][b]);
                    acc[ri][b] = fmaf(wreg[ri][i4].w, h4.w, acc[ri][b]);
                }
            }
        }
        __syncthreads();   // all hc reads done; red aliases hc

        // ---- C1b: dump partials to LDS ----
        #pragma unroll
        for (int ri = 0; ri < 4; ++ri) {
            const int rloc = rg * 4 + ri;
            #pragma unroll
            for (int b = 0; b < BB; ++b)
                sm.u.red[rloc * BB + b][kc] = acc[ri][b];
        }
        __syncthreads();

        // ---- C2: sum 32 partials per gate output ----
        for (int o = tid; o < NROW * BB; o += NTH) {
            float4 sa = make_float4(0.f, 0.f, 0.f, 0.f);
            #pragma unroll
            for (int k4 = 0; k4 < 8; ++k4) {
                const float4 v = *(const float4*)&sm.u.red[o][k4 * 4];
                sa.x += v.x; sa.y += v.y; sa.z += v.z; sa.w += v.w;
            }
            const int rloc = (o * 205) >> 11;   // o/10, valid for o<1024
            const int b = o - rloc * 10;
            sm.gates[rloc][b] = (sa.x + sa.y) + (sa.z + sa.w);
        }
        __syncthreads();

        // ---- D: nonlinearities + state update (80 threads) ----
        if (tid < NCOL * BB) {
            const int j = tid & 7, b = tid >> 3;
            const float gi = sm.gates[j][b]      + sm.bias_s[j];
            const float gf = sm.gates[8 + j][b]  + sm.bias_s[8 + j];
            const float gg = sm.gates[16 + j][b] + sm.bias_s[16 + j];
            const float go = sm.gates[24 + j][b] + sm.bias_s[24 + j];
            float c = sm.cst[j][b];
            c = fsig(gf) * c + fsig(gi) * ftanh(gg);
            const float h = fsig(go) * ftanh(c);
            sm.cst[j][b] = c;
            myring[(size_t)(t & (DEPTH - 1)) * BB * HH + b * HH + s * NCOL + j] = h;
            if (t == TT - 1)
                out[((size_t)l * BB + b) * HH + s * NCOL + j] = c;
            __threadfence();   // drain h stores to device scope before the flag
        }
        __syncthreads();
        if (tid == 0)
            __hip_atomic_fetch_add(&prog[l], 1, __ATOMIC_RELEASE, __HIP_MEMORY_SCOPE_AGENT);
    }
}

__global__ __launch_bounds__(NTH, 1)
void lstm_persistent(const float* __restrict__ x, const float* __restrict__ h0,
                     const float* __restrict__ c0, const float* __restrict__ Wih0,
                     const float* __restrict__ Wih, const float* __restrict__ Whh,
                     const float* __restrict__ bih, const float* __restrict__ bhh,
                     float* __restrict__ out, int* prog, float* hring)
{
    __shared__ Smem sm;
    const int l = blockIdx.x / GPL;
    const int s = blockIdx.x % GPL;
    if (l == 0)
        run_layer<3>(sm, l, s, x, h0, c0, Wih0, Wih, Whh, bih, bhh, out, prog, hring);
    else
        run_layer<4>(sm, l, s, x, h0, c0, Wih0, Wih, Whh, bih, bhh, out, prog, hring);
}

extern "C" void kernel_launch(void* const* d_in, const int* in_sizes, int n_in,
                              void* d_out, int out_size, void* d_ws, size_t ws_size,
                              hipStream_t stream) {
    const float* x    = (const float*)d_in[0];
    const float* h0   = (const float*)d_in[1];
    const float* c0   = (const float*)d_in[2];
    const float* Wih0 = (const float*)d_in[3];
    const float* Wih  = (const float*)d_in[4];
    const float* Whh  = (const float*)d_in[5];
    const float* bih  = (const float*)d_in[6];
    const float* bhh  = (const float*)d_in[7];
    float* out  = (float*)d_out;

    int*   prog  = (int*)d_ws;                       // 6 per-layer progress counters
    float* hring = (float*)((char*)d_ws + 256);      // [L][DEPTH][B][H] ring

    hipMemsetAsync(d_ws, 0, 256, stream);            // ws is poisoned 0xAA each launch
    hipLaunchKernelGGL(lstm_persistent, dim3(LAYERS * GPL), dim3(NTH), 0, stream,
                       x, h0, c0, Wih0, Wih, Whh, bih, bhh, out, prog, hring);
}

// Round 3
// 24243.431 us; speedup vs baseline: 2.1355x; 2.1355x over previous
//
#include <hip/hip_runtime.h>

#define LAYERS 6
#define BB 10
#define TT 2048
#define II 128
#define HH 256
#define GPL 32          // blocks per layer
#define DEPTH 8         // h ring-buffer depth (power of 2)
#define NTH 256
#define NCOL 8          // h-columns per block
#define NROW 32         // gate rows per block (4 gates x 8 cols)
#define HCSTR 520       // padded LDS stride for h_cat rows
#define REDSTR 36       // padded stride for reduction scratch
#define FLPAD 16        // ints per flag slot (64 B padding)

struct Smem {
    union {
        float hc[BB][HCSTR];            // staged [x_t | h_below | h_own] per batch
        float red[NROW * BB][REDSTR];   // partial-sum scratch (aliased, phase-disjoint)
    } u;
    float gates[NROW][BB];
    float cst[NCOL][BB];
    float bias_s[NROW];
};

__device__ __forceinline__ float fsig(float x) { return 1.0f / (1.0f + __expf(-x)); }
__device__ __forceinline__ float ftanh(float x) {
    x = fminf(fmaxf(x, -15.0f), 15.0f);
    float e = __expf(2.0f * x);
    return (e - 1.0f) / (e + 1.0f);
}

// CH4 = float4-chunks per (thread, batch): 4 -> K=512 (layers 1..5), 3 -> K=384 (layer 0)
template <int CH4>
__device__ void run_layer(Smem& sm, int l, int s,
                          const float* __restrict__ x,
                          const float* __restrict__ h0,
                          const float* __restrict__ c0,
                          const float* __restrict__ Wih0,
                          const float* __restrict__ Wih,
                          const float* __restrict__ Whh,
                          const float* __restrict__ bih,
                          const float* __restrict__ bhh,
                          float* __restrict__ out,
                          int* flags, float* hring)
{
    constexpr int K = CH4 * 128;   // 512 or 384
    constexpr int F = K - HH;      // 256 or 128 (input-feature width)
    const int tid = threadIdx.x;
    const int kc  = tid & 31;      // K-split lane (32 chunks)
    const int rg  = tid >> 5;      // row group 0..7

    const float* WihL = (F == II) ? Wih0 : (Wih + (size_t)(l - 1) * 4 * HH * HH);
    const float* WhhL = Whh + (size_t)l * 4 * HH * HH;

    // ---- persistent weight registers: 4 rows x CH4 float4 ----
    // chunk i4 of lane kc covers K-columns [(i4*32+kc)*4 .. +3]  (kc fastest -> LDS-friendly)
    float4 wreg[4][CH4];
    #pragma unroll
    for (int ri = 0; ri < 4; ++ri) {
        const int rloc = rg * 4 + ri;                            // 0..31
        const int gr = (rloc >> 3) * HH + s * NCOL + (rloc & 7); // global gate row
        #pragma unroll
        for (int i4 = 0; i4 < CH4; ++i4) {
            const int k0 = (i4 * 32 + kc) * 4;
            float tmp[4];
            #pragma unroll
            for (int c = 0; c < 4; ++c) {
                const int kk = k0 + c;
                tmp[c] = (kk < F) ? WihL[(size_t)gr * F + kk]
                                  : WhhL[(size_t)gr * HH + (kk - F)];
            }
            wreg[ri][i4] = make_float4(tmp[0], tmp[1], tmp[2], tmp[3]);
        }
    }
    if (tid < NROW) {
        const int gr = (tid >> 3) * HH + s * NCOL + (tid & 7);
        sm.bias_s[tid] = bih[l * 4 * HH + gr] + bhh[l * 4 * HH + gr];
    }
    if (tid < NCOL * BB) {
        const int j = tid & 7, b = tid >> 3;
        sm.cst[j][b] = c0[((size_t)l * BB + b) * HH + s * NCOL + j];
    }
    __syncthreads();

    float* const myring = hring + (size_t)l * DEPTH * BB * HH;

    for (int t = 0; t < TT; ++t) {
        // ---- A: flag waits. Relaxed polls, single acquire fence after the barrier. ----
        if (tid < 64) {
            const int lane = tid;
            bool act; const int* p; int tgt;
            if (lane < 32) {        // own layer: all blocks finished t-1
                act = (t > 0); p = flags + (l * GPL + lane) * FLPAD; tgt = t;
            } else {                // below layer finished t
                act = (l > 0); p = flags + ((l - 1) * GPL + (lane - 32)) * FLPAD; tgt = t + 1;
            }
            if (__ballot(act)) {
                for (;;) {
                    int v = act ? __hip_atomic_load(p, __ATOMIC_RELAXED, __HIP_MEMORY_SCOPE_AGENT)
                                : 0x7fffffff;
                    if (__ballot(act && v < tgt) == 0) break;
                    __builtin_amdgcn_s_sleep(2);
                }
            }
        } else if (tid < 128) {     // back-pressure: consumer done with slot t-DEPTH
            const int lane = tid - 64;
            const bool act = (lane < 32) && (l < LAYERS - 1) && (t >= DEPTH);
            const int* p = flags + ((l + 1) * GPL + (lane & 31)) * FLPAD;
            const int tgt = t - DEPTH + 1;
            if (__ballot(act)) {
                for (;;) {
                    int v = act ? __hip_atomic_load(p, __ATOMIC_RELAXED, __HIP_MEMORY_SCOPE_AGENT)
                                : 0x7fffffff;
                    if (__ballot(act && v < tgt) == 0) break;
                    __builtin_amdgcn_s_sleep(2);
                }
            }
        }
        __syncthreads();
        __builtin_amdgcn_fence(__ATOMIC_ACQUIRE, "agent");

        // ---- B: stage h_cat = [x_t | h_below , h_own] into LDS ----
        if (F == II) {  // layer 0: x feature block
            for (int q = tid; q < BB * (II / 4); q += NTH) {
                const int b = q >> 5, qq = q & 31;
                *(float4*)&sm.u.hc[b][qq * 4] =
                    *(const float4*)&x[((size_t)b * TT + t) * II + qq * 4];
            }
        } else {
            const float* below = hring + ((size_t)(l - 1) * DEPTH + (t & (DEPTH - 1))) * BB * HH;
            for (int q = tid; q < BB * (HH / 4); q += NTH) {
                const int b = q >> 6, qq = q & 63;
                *(float4*)&sm.u.hc[b][qq * 4] = *(const float4*)&below[b * HH + qq * 4];
            }
        }
        {
            const float* own = (t == 0) ? (h0 + (size_t)l * BB * HH)
                                        : (myring + (size_t)((t - 1) & (DEPTH - 1)) * BB * HH);
            for (int q = tid; q < BB * (HH / 4); q += NTH) {
                const int b = q >> 6, qq = q & 63;
                *(float4*)&sm.u.hc[b][F + qq * 4] = *(const float4*)&own[b * HH + qq * 4];
            }
        }
        __syncthreads();

        // ---- C1: register-blocked partial dots (4 rows x 10 batches) ----
        float acc[4][BB];
        #pragma unroll
        for (int ri = 0; ri < 4; ++ri)
            #pragma unroll
            for (int b = 0; b < BB; ++b) acc[ri][b] = 0.0f;

        #pragma unroll
        for (int i4 = 0; i4 < CH4; ++i4) {
            const int col = (i4 * 32 + kc) * 4;   // kc fastest: contiguous lanes -> no conflicts
            #pragma unroll
            for (int b = 0; b < BB; ++b) {
                const float4 h4 = *(const float4*)&sm.u.hc[b][col];
                #pragma unroll
                for (int ri = 0; ri < 4; ++ri) {
                    acc[ri][b] = fmaf(wreg[ri][i4].x, h4.x, acc[ri][b]);
                    acc[ri][b] = fmaf(wreg[ri][i4].y, h4.y, acc[ri][b]);
                    acc[ri][b] = fmaf(wreg[ri][i4].z, h4.z, acc[ri][b]);
                    acc[ri][b] = fmaf(wreg[ri][i4].w, h4.w, acc[ri][b]);
                }
            }
        }
        __syncthreads();   // all hc reads done; red aliases hc

        // ---- C1b: dump partials to LDS ----
        #pragma unroll
        for (int ri = 0; ri < 4; ++ri) {
            const int rloc = rg * 4 + ri;
            #pragma unroll
            for (int b = 0; b < BB; ++b)
                sm.u.red[rloc * BB + b][kc] = acc[ri][b];
        }
        __syncthreads();

        // ---- C2: sum 32 partials per gate output ----
        for (int o = tid; o < NROW * BB; o += NTH) {
            float4 sa = make_float4(0.f, 0.f, 0.f, 0.f);
            #pragma unroll
            for (int k4 = 0; k4 < 8; ++k4) {
                const float4 v = *(const float4*)&sm.u.red[o][k4 * 4];
                sa.x += v.x; sa.y += v.y; sa.z += v.z; sa.w += v.w;
            }
            const int rloc = (o * 205) >> 11;   // o/10, valid for o<1024
            const int b = o - rloc * 10;
            sm.gates[rloc][b] = (sa.x + sa.y) + (sa.z + sa.w);
        }
        __syncthreads();

        // ---- D: nonlinearities + state update (80 threads) ----
        if (tid < NCOL * BB) {
            const int j = tid & 7, b = tid >> 3;
            const float gi = sm.gates[j][b]      + sm.bias_s[j];
            const float gf = sm.gates[8 + j][b]  + sm.bias_s[8 + j];
            const float gg = sm.gates[16 + j][b] + sm.bias_s[16 + j];
            const float go = sm.gates[24 + j][b] + sm.bias_s[24 + j];
            float c = sm.cst[j][b];
            c = fsig(gf) * c + fsig(gi) * ftanh(gg);
            const float h = fsig(go) * ftanh(c);
            sm.cst[j][b] = c;
            // agent-scope bypassing store: lands at the coherence point
            __hip_atomic_store(&myring[(size_t)(t & (DEPTH - 1)) * BB * HH + b * HH + s * NCOL + j],
                               h, __ATOMIC_RELAXED, __HIP_MEMORY_SCOPE_AGENT);
            if (t == TT - 1)
                out[((size_t)l * BB + b) * HH + s * NCOL + j] = c;
        }
        __syncthreads();   // drains every wave's stores (vmcnt(0) before s_barrier)
        if (tid == 0)
            __hip_atomic_store(flags + (l * GPL + s) * FLPAD, t + 1,
                               __ATOMIC_RELEASE, __HIP_MEMORY_SCOPE_AGENT);
    }
}

__global__ __launch_bounds__(NTH, 1)
void lstm_persistent(const float* __restrict__ x, const float* __restrict__ h0,
                     const float* __restrict__ c0, const float* __restrict__ Wih0,
                     const float* __restrict__ Wih, const float* __restrict__ Whh,
                     const float* __restrict__ bih, const float* __restrict__ bhh,
                     float* __restrict__ out, int* flags, float* hring)
{
    __shared__ Smem sm;
    const int l = blockIdx.x / GPL;
    const int s = blockIdx.x % GPL;
    if (l == 0)
        run_layer<3>(sm, l, s, x, h0, c0, Wih0, Wih, Whh, bih, bhh, out, flags, hring);
    else
        run_layer<4>(sm, l, s, x, h0, c0, Wih0, Wih, Whh, bih, bhh, out, flags, hring);
}

extern "C" void kernel_launch(void* const* d_in, const int* in_sizes, int n_in,
                              void* d_out, int out_size, void* d_ws, size_t ws_size,
                              hipStream_t stream) {
    const float* x    = (const float*)d_in[0];
    const float* h0   = (const float*)d_in[1];
    const float* c0   = (const float*)d_in[2];
    const float* Wih0 = (const float*)d_in[3];
    const float* Wih  = (const float*)d_in[4];
    const float* Whh  = (const float*)d_in[5];
    const float* bih  = (const float*)d_in[6];
    const float* bhh  = (const float*)d_in[7];
    float* out  = (float*)d_out;

    int*   flags = (int*)d_ws;                        // [L][GPL] padded to 64B each
    float* hring = (float*)((char*)d_ws + 16384);     // [L][DEPTH][B][H] ring

    (void)hipMemsetAsync(d_ws, 0, 16384, stream);     // ws is poisoned 0xAA each launch
    hipLaunchKernelGGL(lstm_persistent, dim3(LAYERS * GPL), dim3(NTH), 0, stream,
                       x, h0, c0, Wih0, Wih, Whh, bih, bhh, out, flags, hring);
}

// Round 4
// 13440.358 us; speedup vs baseline: 3.8520x; 1.8038x over previous
//
#include <hip/hip_runtime.h>

#define LAYERS 6
#define BB 10
#define TT 2048
#define II 128
#define HH 256
#define GPL 32          // blocks per layer
#define DEPTH 8         // h ring-buffer depth (power of 2)
#define NTH 256
#define NCOL 8          // h-columns per block
#define NROW 32         // gate rows per block (4 gates x 8 cols)
#define HCSTR 520       // padded LDS stride for h_cat rows
#define REDSTR 36       // padded stride for reduction scratch
#define FLPAD 16        // ints per flag slot (64 B padding)

struct Smem {
    union {
        float hc[BB][HCSTR];            // staged [x_t | h_below | h_own] per batch
        float red[NROW * BB][REDSTR];   // partial-sum scratch (aliased, phase-disjoint)
    } u;
    float gates[NROW][BB];
    float cst[NCOL][BB];
    float bias_s[NROW];
};

__device__ __forceinline__ float fsig(float x) { return 1.0f / (1.0f + __expf(-x)); }
__device__ __forceinline__ float ftanh(float x) {
    x = fminf(fmaxf(x, -15.0f), 15.0f);
    float e = __expf(2.0f * x);
    return (e - 1.0f) / (e + 1.0f);
}

__device__ __forceinline__ float ld_agent(const float* p) {
    // coherent LLC read (sc1) - same path the flag polling uses; no fence needed
    return __hip_atomic_load(p, __ATOMIC_RELAXED, __HIP_MEMORY_SCOPE_AGENT);
}

// CH4 = float4-chunks per (thread, batch): 4 -> K=512 (layers 1..5), 3 -> K=384 (layer 0)
template <int CH4>
__device__ void run_layer(Smem& sm, int l, int s,
                          const float* __restrict__ x,
                          const float* __restrict__ h0,
                          const float* __restrict__ c0,
                          const float* __restrict__ Wih0,
                          const float* __restrict__ Wih,
                          const float* __restrict__ Whh,
                          const float* __restrict__ bih,
                          const float* __restrict__ bhh,
                          float* __restrict__ out,
                          int* flags, float* hring)
{
    constexpr int K = CH4 * 128;   // 512 or 384
    constexpr int F = K - HH;      // 256 or 128 (input-feature width)
    const int tid = threadIdx.x;
    const int kc  = tid & 31;      // K-split lane (32 chunks)
    const int rg  = tid >> 5;      // row group 0..7

    const float* WihL = (F == II) ? Wih0 : (Wih + (size_t)(l - 1) * 4 * HH * HH);
    const float* WhhL = Whh + (size_t)l * 4 * HH * HH;

    // ---- persistent weight registers: 4 rows x CH4 float4 ----
    float4 wreg[4][CH4];
    #pragma unroll
    for (int ri = 0; ri < 4; ++ri) {
        const int rloc = rg * 4 + ri;                            // 0..31
        const int gr = (rloc >> 3) * HH + s * NCOL + (rloc & 7); // global gate row
        #pragma unroll
        for (int i4 = 0; i4 < CH4; ++i4) {
            const int k0 = (i4 * 32 + kc) * 4;
            float tmp[4];
            #pragma unroll
            for (int c = 0; c < 4; ++c) {
                const int kk = k0 + c;
                tmp[c] = (kk < F) ? WihL[(size_t)gr * F + kk]
                                  : WhhL[(size_t)gr * HH + (kk - F)];
            }
            wreg[ri][i4] = make_float4(tmp[0], tmp[1], tmp[2], tmp[3]);
        }
    }
    if (tid < NROW) {
        const int gr = (tid >> 3) * HH + s * NCOL + (tid & 7);
        sm.bias_s[tid] = bih[l * 4 * HH + gr] + bhh[l * 4 * HH + gr];
    }
    if (tid < NCOL * BB) {
        const int j = tid & 7, b = tid >> 3;
        sm.cst[j][b] = c0[((size_t)l * BB + b) * HH + s * NCOL + j];
    }
    __syncthreads();

    float* const myring = hring + (size_t)l * DEPTH * BB * HH;

    for (int t = 0; t < TT; ++t) {
        // ---- A: flag waits. Relaxed agent polls; NO cache-invalidating fence. ----
        if (tid < 64) {
            const int lane = tid;
            bool act; const int* p; int tgt;
            if (lane < 32) {        // own layer: all blocks finished t-1
                act = (t > 0); p = flags + (l * GPL + lane) * FLPAD; tgt = t;
            } else {                // below layer finished t
                act = (l > 0); p = flags + ((l - 1) * GPL + (lane - 32)) * FLPAD; tgt = t + 1;
            }
            if (__ballot(act)) {
                for (;;) {
                    int v = act ? __hip_atomic_load(p, __ATOMIC_RELAXED, __HIP_MEMORY_SCOPE_AGENT)
                                : 0x7fffffff;
                    if (__ballot(act && v < tgt) == 0) break;
                    __builtin_amdgcn_s_sleep(2);
                }
            }
        } else if (tid < 128) {     // back-pressure: consumer done with slot t-DEPTH
            const int lane = tid - 64;
            const bool act = (lane < 32) && (l < LAYERS - 1) && (t >= DEPTH);
            const int* p = flags + ((l + 1) * GPL + (lane & 31)) * FLPAD;
            const int tgt = t - DEPTH + 1;
            if (__ballot(act)) {
                for (;;) {
                    int v = act ? __hip_atomic_load(p, __ATOMIC_RELAXED, __HIP_MEMORY_SCOPE_AGENT)
                                : 0x7fffffff;
                    if (__ballot(act && v < tgt) == 0) break;
                    __builtin_amdgcn_s_sleep(2);
                }
            }
        }
        __syncthreads();
        asm volatile("" ::: "memory");   // compiler-only ordering; no HW cache ops

        // ---- B: stage h_cat = [x_t | h_below , h_own] into LDS ----
        // batch all coherent loads into registers first (one waitcnt), then LDS writes
        {
            const float* own = (t == 0) ? (h0 + (size_t)l * BB * HH)
                                        : (myring + (size_t)((t - 1) & (DEPTH - 1)) * BB * HH);
            float to_[10];
            #pragma unroll
            for (int i = 0; i < 10; ++i)
                to_[i] = ld_agent(&own[tid + i * NTH]);

            if (F == II) {  // layer 0: x feature block (read-only, plain cached loads)
                for (int q = tid; q < BB * (II / 4); q += NTH) {
                    const int b = q >> 5, qq = q & 31;
                    *(float4*)&sm.u.hc[b][qq * 4] =
                        *(const float4*)&x[((size_t)b * TT + t) * II + qq * 4];
                }
            } else {
                const float* below = hring + ((size_t)(l - 1) * DEPTH + (t & (DEPTH - 1))) * BB * HH;
                float tb[10];
                #pragma unroll
                for (int i = 0; i < 10; ++i)
                    tb[i] = ld_agent(&below[tid + i * NTH]);
                #pragma unroll
                for (int i = 0; i < 10; ++i) {
                    const int q = tid + i * NTH;
                    sm.u.hc[q >> 8][q & 255] = tb[i];
                }
            }
            #pragma unroll
            for (int i = 0; i < 10; ++i) {
                const int q = tid + i * NTH;
                sm.u.hc[q >> 8][F + (q & 255)] = to_[i];
            }
        }
        __syncthreads();

        // ---- C1: register-blocked partial dots (4 rows x 10 batches) ----
        float acc[4][BB];
        #pragma unroll
        for (int ri = 0; ri < 4; ++ri)
            #pragma unroll
            for (int b = 0; b < BB; ++b) acc[ri][b] = 0.0f;

        #pragma unroll
        for (int i4 = 0; i4 < CH4; ++i4) {
            const int col = (i4 * 32 + kc) * 4;   // kc fastest: contiguous lanes -> no conflicts
            #pragma unroll
            for (int b = 0; b < BB; ++b) {
                const float4 h4 = *(const float4*)&sm.u.hc[b][col];
                #pragma unroll
                for (int ri = 0; ri < 4; ++ri) {
                    acc[ri][b] = fmaf(wreg[ri][i4].x, h4.x, acc[ri][b]);
                    acc[ri][b] = fmaf(wreg[ri][i4].y, h4.y, acc[ri][b]);
                    acc[ri][b] = fmaf(wreg[ri][i4].z, h4.z, acc[ri][b]);
                    acc[ri][b] = fmaf(wreg[ri][i4].w, h4.w, acc[ri][b]);
                }
            }
        }
        __syncthreads();   // all hc reads done; red aliases hc

        // ---- C1b: dump partials to LDS ----
        #pragma unroll
        for (int ri = 0; ri < 4; ++ri) {
            const int rloc = rg * 4 + ri;
            #pragma unroll
            for (int b = 0; b < BB; ++b)
                sm.u.red[rloc * BB + b][kc] = acc[ri][b];
        }
        __syncthreads();

        // ---- C2: sum 32 partials per gate output ----
        for (int o = tid; o < NROW * BB; o += NTH) {
            float4 sa = make_float4(0.f, 0.f, 0.f, 0.f);
            #pragma unroll
            for (int k4 = 0; k4 < 8; ++k4) {
                const float4 v = *(const float4*)&sm.u.red[o][k4 * 4];
                sa.x += v.x; sa.y += v.y; sa.z += v.z; sa.w += v.w;
            }
            const int rloc = (o * 205) >> 11;   // o/10, valid for o<1024
            const int b = o - rloc * 10;
            sm.gates[rloc][b] = (sa.x + sa.y) + (sa.z + sa.w);
        }
        __syncthreads();

        // ---- D: nonlinearities + state update (80 threads) ----
        if (tid < NCOL * BB) {
            const int j = tid & 7, b = tid >> 3;
            const float gi = sm.gates[j][b]      + sm.bias_s[j];
            const float gf = sm.gates[8 + j][b]  + sm.bias_s[8 + j];
            const float gg = sm.gates[16 + j][b] + sm.bias_s[16 + j];
            const float go = sm.gates[24 + j][b] + sm.bias_s[24 + j];
            float c = sm.cst[j][b];
            c = fsig(gf) * c + fsig(gi) * ftanh(gg);
            const float h = fsig(go) * ftanh(c);
            sm.cst[j][b] = c;
            // sc1 write-through store: lands at the coherence point (LLC)
            __hip_atomic_store(&myring[(size_t)(t & (DEPTH - 1)) * BB * HH + b * HH + s * NCOL + j],
                               h, __ATOMIC_RELAXED, __HIP_MEMORY_SCOPE_AGENT);
            if (t == TT - 1)
                out[((size_t)l * BB + b) * HH + s * NCOL + j] = c;
        }
        __syncthreads();   // per-wave vmcnt(0) before s_barrier drains the h stores
        if (tid == 0)
            __hip_atomic_store(flags + (l * GPL + s) * FLPAD, t + 1,
                               __ATOMIC_RELEASE, __HIP_MEMORY_SCOPE_AGENT);
    }
}

__global__ __launch_bounds__(NTH, 1)
void lstm_persistent(const float* __restrict__ x, const float* __restrict__ h0,
                     const float* __restrict__ c0, const float* __restrict__ Wih0,
                     const float* __restrict__ Wih, const float* __restrict__ Whh,
                     const float* __restrict__ bih, const float* __restrict__ bhh,
                     float* __restrict__ out, int* flags, float* hring)
{
    __shared__ Smem sm;
    const int l = blockIdx.x / GPL;
    const int s = blockIdx.x % GPL;
    if (l == 0)
        run_layer<3>(sm, l, s, x, h0, c0, Wih0, Wih, Whh, bih, bhh, out, flags, hring);
    else
        run_layer<4>(sm, l, s, x, h0, c0, Wih0, Wih, Whh, bih, bhh, out, flags, hring);
}

extern "C" void kernel_launch(void* const* d_in, const int* in_sizes, int n_in,
                              void* d_out, int out_size, void* d_ws, size_t ws_size,
                              hipStream_t stream) {
    const float* x    = (const float*)d_in[0];
    const float* h0   = (const float*)d_in[1];
    const float* c0   = (const float*)d_in[2];
    const float* Wih0 = (const float*)d_in[3];
    const float* Wih  = (const float*)d_in[4];
    const float* Whh  = (const float*)d_in[5];
    const float* bih  = (const float*)d_in[6];
    const float* bhh  = (const float*)d_in[7];
    float* out  = (float*)d_out;

    int*   flags = (int*)d_ws;                        // [L][GPL] padded to 64B each
    float* hring = (float*)((char*)d_ws + 16384);     // [L][DEPTH][B][H] ring

    (void)hipMemsetAsync(d_ws, 0, 16384, stream);     // ws is poisoned 0xAA each launch
    hipLaunchKernelGGL(lstm_persistent, dim3(LAYERS * GPL), dim3(NTH), 0, stream,
                       x, h0, c0, Wih0, Wih, Whh, bih, bhh, out, flags, hring);
}